// Round 5
// baseline (283.304 us; speedup 1.0000x reference)
//
#include <hip/hip_runtime.h>

typedef __attribute__((ext_vector_type(8))) short short8;
typedef __attribute__((ext_vector_type(4))) float f32x4;

#define HF 256
#define WF 256

__device__ __forceinline__ ushort f2bf(float f) {
    uint u = __builtin_bit_cast(uint, f);
    u = (u + 0x7FFFu + ((u >> 16) & 1u)) >> 16;
    return (ushort)u;
}
__device__ __forceinline__ uint pack2(float a, float b) {
    return (uint)f2bf(a) | ((uint)f2bf(b) << 16);
}
__device__ __forceinline__ float prelu(float v, float al) { return v >= 0.f ? v : al * v; }

// ---------------------------------------------------------------------------
// Weight prep A: w[o][c][3][3] f32 -> wT[tap][o][c] bf16 (for the two convs)
// ---------------------------------------------------------------------------
__global__ __launch_bounds__(256) void k_wprep(const float* __restrict__ w1,
                                               const float* __restrict__ w2,
                                               ushort* __restrict__ wT1,
                                               ushort* __restrict__ wT2) {
    int idx = blockIdx.x * 256 + threadIdx.x;   // [tap][o][c] : 9*64*64 = 36864
    int tap = idx >> 12;
    int oc  = idx & 4095;
    int src = oc * 9 + tap;
    wT1[idx] = f2bf(w1[src]);
    wT2[idx] = f2bf(w2[src]);
}

// ---------------------------------------------------------------------------
// Weight prep B: wup[c][o][p][q] f32 -> wupT[out = (p*2+q)*64 + o][c] bf16
// ---------------------------------------------------------------------------
__global__ __launch_bounds__(256) void k_wprep_up(const float* __restrict__ wup,
                                                  ushort* __restrict__ wupT) {
    int idx = blockIdx.x * 256 + threadIdx.x;   // 256*128 = 32768
    int out = idx >> 7;
    int c   = idx & 127;
    int k   = out >> 6;       // p*2+q
    int o   = out & 63;
    wupT[idx] = f2bf(wup[c * 256 + o * 4 + k]);
}

// ---------------------------------------------------------------------------
// ConvTranspose2d k=2 s=2 for b=2,3 via bf16 MFMA -> upB NHWC [z][y][x][64]
// (unchanged from R4 — known good)
// ---------------------------------------------------------------------------
__global__ __launch_bounds__(512) void k_upsample_mfma(const float* __restrict__ x1,
                                                       const ushort* __restrict__ wupT,
                                                       const float* __restrict__ bup,
                                                       ushort* __restrict__ upB) {
    __shared__ __align__(16) char lds[81920];

    const int t   = threadIdx.x;
    const int l   = t & 63;
    const int l15 = l & 15;
    const int l4  = l >> 4;
    const int w   = t >> 6;
    const int pg  = w & 3;
    const int oh  = w >> 2;
    const int i   = blockIdx.x >> 1;
    const int j0  = (blockIdx.x & 1) * 64;
    const int z   = blockIdx.y;
    const int gb  = 2 + z;

    {
        const int j  = t & 63;
        const int cg = t >> 6;
        const size_t base = ((size_t)gb * 128) * 16384 + (size_t)i * 128 + j0 + j;
        float xv[16];
#pragma unroll
        for (int r = 0; r < 2; ++r)
#pragma unroll
            for (int cc = 0; cc < 8; ++cc)
                xv[r * 8 + cc] = x1[base + (size_t)(cg * 16 + r * 8 + cc) * 16384];
#pragma unroll
        for (int r = 0; r < 2; ++r) {
            short8 pk;
#pragma unroll
            for (int cc = 0; cc < 8; ++cc) pk[cc] = (short)f2bf(xv[r * 8 + cc]);
            int ad = (j * 256 + (cg * 16 + r * 8) * 2) ^ ((j & 15) << 4);
            *(short8*)(lds + ad) = pk;
        }
    }
    {
        const uint4* src = (const uint4*)wupT;
#pragma unroll
        for (int rep = 0; rep < 8; ++rep) {
            int q   = rep * 512 + t;
            int out = q >> 4, c16 = q & 15;
            int ad  = 16384 + ((out * 256 + c16 * 16) ^ ((out & 15) << 4));
            *(uint4*)(lds + ad) = src[q];
        }
    }
    float bvv[4];
#pragma unroll
    for (int ob = 0; ob < 4; ++ob) bvv[ob] = bup[ob * 16 + l15];
    __syncthreads();

    f32x4 acc[2][4];
#pragma unroll
    for (int kk = 0; kk < 2; ++kk)
#pragma unroll
        for (int ob = 0; ob < 4; ++ob) acc[kk][ob] = (f32x4){0.f, 0.f, 0.f, 0.f};

#pragma unroll
    for (int ks = 0; ks < 4; ++ks) {
        const int cb = ks * 64 + (l4 << 4);
        const int rowA = pg * 16 + l15;
        short8 xfr = *(const short8*)(lds + ((rowA * 256 + cb) ^ ((rowA & 15) << 4)));
#pragma unroll
        for (int kk = 0; kk < 2; ++kk)
#pragma unroll
            for (int ob = 0; ob < 4; ++ob) {
                int out = (oh * 2 + kk) * 64 + ob * 16 + l15;
                short8 wfr = *(const short8*)(lds + 16384 +
                              ((out * 256 + cb) ^ ((out & 15) << 4)));
                acc[kk][ob] = __builtin_amdgcn_mfma_f32_16x16x32_bf16(xfr, wfr, acc[kk][ob], 0, 0, 0);
            }
    }
    __syncthreads();

    ushort* OUT = (ushort*)lds;
#pragma unroll
    for (int kk = 0; kk < 2; ++kk) {
        const int k = oh * 2 + kk, p = k >> 1, q = k & 1;
#pragma unroll
        for (int ob = 0; ob < 4; ++ob) {
            const int o = ob * 16 + l15;
#pragma unroll
            for (int r = 0; r < 4; ++r) {
                int jl = pg * 16 + l4 * 4 + r;
                int x  = 2 * jl + q;
                OUT[(p * 128 + x) * 64 + o] = f2bf(acc[kk][ob][r] + bvv[ob]);
            }
        }
    }
    __syncthreads();

#pragma unroll
    for (int rep = 0; rep < 4; ++rep) {
        int idx = rep * 512 + t;
        int p   = idx >> 10;
        int y   = 2 * i + p;
        uint4 v = *(const uint4*)(lds + idx * 16);
        size_t g = (size_t)(z * HF + y) * 2048 + (size_t)j0 * 16 + (idx & 1023);
        ((uint4*)upB)[g] = v;
    }
}

// ---------------------------------------------------------------------------
// 3x3 SAME conv 64->64 + bias + PReLU via bf16 MFMA.
// v2: weights in REGISTERS (wave owns 16 couts, 18 short8 = all 9 taps),
// input tile 32x8 (+halo -> 10x34x64) in LDS, ZERO barriers in the K-loop.
// Block 256 thr / 4 waves, all waves cover all 256 positions (16 M-frags).
// 2 blocks/CU (launch_bounds (256,2)); LDS 43.5 KB.
// ---------------------------------------------------------------------------
template<int IN_MODE, int OUT_NHWC>
__global__ __launch_bounds__(256, 2) void k_conv(const float* __restrict__ x2,
                                                 const ushort* __restrict__ upB,
                                                 const ushort* __restrict__ inB,
                                                 const ushort* __restrict__ wT,
                                                 const float* __restrict__ bias,
                                                 const float* __restrict__ alpha,
                                                 ushort* __restrict__ outB,
                                                 float* __restrict__ outF) {
    __shared__ __align__(16) ushort inL[10 * 34 * 64];   // [r][x][c], XOR-swizzled on x

    const int t   = threadIdx.x;
    const int w   = t >> 6;          // wave id -> cout group
    const int l   = t & 63;
    const int l15 = l & 15;
    const int l4  = l >> 4;
    const int o0  = w * 16;
    const int x0  = (blockIdx.x & 7) * 32;
    const int y0  = (blockIdx.x >> 3) * 8;
    const int b   = blockIdx.y;

    // ---- weight fragments for this wave's 16 couts: all 9 taps, both ks
    // wreg[tap][ks][lane] = wT[tap][o0+l15][ks*32 + l4*8 .. +8]
    short8 wreg[9][2];
    {
        const ushort* wbase = wT + (size_t)(o0 + l15) * 64 + l4 * 8;
#pragma unroll
        for (int tap = 0; tap < 9; ++tap)
#pragma unroll
            for (int ks = 0; ks < 2; ++ks)
                wreg[tap][ks] = *(const short8*)(wbase + tap * 4096 + ks * 32);
    }

    // ---- stage input tile (10 x 34 x 64ch), zero-padded halo
    for (int q = t; q < 10 * 34 * 8; q += 256) {
        int r   = q / 272;
        int rem = q - r * 272;
        int x   = rem >> 3;
        int c8  = rem & 7;
        int gy = y0 - 1 + r;
        int gx = x0 - 1 + x;
        uint4 v = make_uint4(0u, 0u, 0u, 0u);
        if ((unsigned)gy < HF && (unsigned)gx < WF) {
            size_t pos = (size_t)(b * HF + gy) * WF + gx;
            if (IN_MODE == 1) {
                v = *(const uint4*)(inB + pos * 64 + c8 * 8);
            } else if (b < 2) {
                const float4* s = (const float4*)(x2 + pos * 64 + c8 * 8);
                float4 u0 = s[0], u1 = s[1];
                v = make_uint4(pack2(u0.x, u0.y), pack2(u0.z, u0.w),
                               pack2(u1.x, u1.y), pack2(u1.z, u1.w));
            } else {
                size_t p2 = (size_t)((b - 2) * HF + gy) * WF + gx;
                v = *(const uint4*)(upB + p2 * 64 + c8 * 8);
            }
        }
        int ad = (q * 16) ^ ((x & 7) << 4);
        *(uint4*)((char*)inL + ad) = v;
    }
    __syncthreads();

    f32x4 acc[16];
#pragma unroll
    for (int f = 0; f < 16; ++f) acc[f] = (f32x4){0.f, 0.f, 0.f, 0.f};

    // ---- main loop: no barriers, no LDS weight traffic
#pragma unroll
    for (int tap = 0; tap < 9; ++tap) {
        const int ky = tap / 3, kx = tap % 3;
#pragma unroll
        for (int ks = 0; ks < 2; ++ks) {
#pragma unroll
            for (int f = 0; f < 16; ++f) {
                int ry = (f >> 1) + ky;                 // input LDS row
                int xl = (f & 1) * 16 + l15 + kx;       // input LDS col
                int ad = ((ry * 34 + xl) * 128 + ks * 64 + (l4 << 4)) ^ ((xl & 7) << 4);
                short8 ifr = *(const short8*)((const char*)inL + ad);
                if (OUT_NHWC)
                    acc[f] = __builtin_amdgcn_mfma_f32_16x16x32_bf16(
                        wreg[tap][ks], ifr, acc[f], 0, 0, 0);    // D: row=cout, col=pos
                else
                    acc[f] = __builtin_amdgcn_mfma_f32_16x16x32_bf16(
                        ifr, wreg[tap][ks], acc[f], 0, 0, 0);    // D: row=pos, col=cout
            }
        }
    }

    const float al = alpha[0];
    if (OUT_NHWC) {
        const float4 bv4 = *(const float4*)(bias + o0 + (l4 << 2));
#pragma unroll
        for (int f = 0; f < 16; ++f) {
            f32x4 v = acc[f];
            uint lo = pack2(prelu(v.x + bv4.x, al), prelu(v.y + bv4.y, al));
            uint hi = pack2(prelu(v.z + bv4.z, al), prelu(v.w + bv4.w, al));
            int y = y0 + (f >> 1);
            int x = x0 + (f & 1) * 16 + l15;
            *(uint2*)(outB + ((size_t)(b * HF + y) * WF + x) * 64 + o0 + (l4 << 2)) =
                make_uint2(lo, hi);
        }
    } else {
        const float bb = bias[o0 + l15];
        const int cout = o0 + l15;
#pragma unroll
        for (int f = 0; f < 16; ++f) {
            f32x4 v = acc[f];
            float4 st;
            st.x = prelu(v.x + bb, al);
            st.y = prelu(v.y + bb, al);
            st.z = prelu(v.z + bb, al);
            st.w = prelu(v.w + bb, al);
            int y  = y0 + (f >> 1);
            int xb = x0 + (f & 1) * 16 + (l4 << 2);
            *(float4*)(outF + (((size_t)b * 64 + cout) << 16) + y * WF + xb) = st;
        }
    }
}

// ---------------------------------------------------------------------------
extern "C" void kernel_launch(void* const* d_in, const int* in_sizes, int n_in,
                              void* d_out, int out_size, void* d_ws, size_t ws_size,
                              hipStream_t stream) {
    const float* x1  = (const float*)d_in[0];
    const float* x2  = (const float*)d_in[1];
    const float* wup = (const float*)d_in[2];
    const float* bup = (const float*)d_in[3];
    const float* w1  = (const float*)d_in[4];
    const float* b1  = (const float*)d_in[5];
    const float* a1  = (const float*)d_in[6];
    const float* w2  = (const float*)d_in[7];
    const float* b2  = (const float*)d_in[8];
    const float* a2  = (const float*)d_in[9];

    char* ws = (char*)d_ws;
    ushort* upB  = (ushort*)ws;                          // 16 MiB (b=2,3 NHWC bf16)
    ushort* hB   = (ushort*)(ws + (size_t)(16 << 20));   // 32 MiB (NHWC bf16)
    ushort* wT1  = (ushort*)(ws + (size_t)(48 << 20));   // 72 KiB
    ushort* wT2  = wT1 + 9 * 64 * 64;                    // 72 KiB
    ushort* wupT = wT2 + 9 * 64 * 64;                    // 64 KiB
    float* out = (float*)d_out;

    k_wprep<<<144, 256, 0, stream>>>(w1, w2, wT1, wT2);
    k_wprep_up<<<128, 256, 0, stream>>>(wup, wupT);
    k_upsample_mfma<<<dim3(256, 2), 512, 0, stream>>>(x1, wupT, bup, upB);
    k_conv<0, 1><<<dim3(256, 4), 256, 0, stream>>>(x2, upB, nullptr, wT1, b1, a1, hB, nullptr);
    k_conv<1, 0><<<dim3(256, 4), 256, 0, stream>>>(nullptr, nullptr, hB, wT2, b2, a2, nullptr, out);
}

// Round 6
// 134.811 us; speedup vs baseline: 2.1015x; 2.1015x over previous
//
#include <hip/hip_runtime.h>

typedef __attribute__((ext_vector_type(8))) short short8;
typedef __attribute__((ext_vector_type(4))) float f32x4;

#define HF 256
#define WF 256

__device__ __forceinline__ ushort f2bf(float f) {
    uint u = __builtin_bit_cast(uint, f);
    u = (u + 0x7FFFu + ((u >> 16) & 1u)) >> 16;
    return (ushort)u;
}
__device__ __forceinline__ uint pack2(float a, float b) {
    return (uint)f2bf(a) | ((uint)f2bf(b) << 16);
}
__device__ __forceinline__ float prelu(float v, float al) { return v >= 0.f ? v : al * v; }

// ---------------------------------------------------------------------------
// Weight prep A: w[o][c][3][3] f32 -> wT[tap][o][c] bf16 (for the two convs)
// ---------------------------------------------------------------------------
__global__ __launch_bounds__(256) void k_wprep(const float* __restrict__ w1,
                                               const float* __restrict__ w2,
                                               ushort* __restrict__ wT1,
                                               ushort* __restrict__ wT2) {
    int idx = blockIdx.x * 256 + threadIdx.x;   // [tap][o][c] : 9*64*64 = 36864
    int tap = idx >> 12;
    int oc  = idx & 4095;
    int src = oc * 9 + tap;
    wT1[idx] = f2bf(w1[src]);
    wT2[idx] = f2bf(w2[src]);
}

// ---------------------------------------------------------------------------
// Weight prep B: wup[c][o][p][q] f32 -> wupT[out = (p*2+q)*64 + o][c] bf16
// ---------------------------------------------------------------------------
__global__ __launch_bounds__(256) void k_wprep_up(const float* __restrict__ wup,
                                                  ushort* __restrict__ wupT) {
    int idx = blockIdx.x * 256 + threadIdx.x;   // 256*128 = 32768
    int out = idx >> 7;
    int c   = idx & 127;
    int k   = out >> 6;       // p*2+q
    int o   = out & 63;
    wupT[idx] = f2bf(wup[c * 256 + o * 4 + k]);
}

// ---------------------------------------------------------------------------
// ConvTranspose2d k=2 s=2 for b=2,3 via bf16 MFMA -> upB NHWC [z][y][x][64]
// (unchanged — known good)
// ---------------------------------------------------------------------------
__global__ __launch_bounds__(512) void k_upsample_mfma(const float* __restrict__ x1,
                                                       const ushort* __restrict__ wupT,
                                                       const float* __restrict__ bup,
                                                       ushort* __restrict__ upB) {
    __shared__ __align__(16) char lds[81920];

    const int t   = threadIdx.x;
    const int l   = t & 63;
    const int l15 = l & 15;
    const int l4  = l >> 4;
    const int w   = t >> 6;
    const int pg  = w & 3;
    const int oh  = w >> 2;
    const int i   = blockIdx.x >> 1;
    const int j0  = (blockIdx.x & 1) * 64;
    const int z   = blockIdx.y;
    const int gb  = 2 + z;

    {
        const int j  = t & 63;
        const int cg = t >> 6;
        const size_t base = ((size_t)gb * 128) * 16384 + (size_t)i * 128 + j0 + j;
        float xv[16];
#pragma unroll
        for (int r = 0; r < 2; ++r)
#pragma unroll
            for (int cc = 0; cc < 8; ++cc)
                xv[r * 8 + cc] = x1[base + (size_t)(cg * 16 + r * 8 + cc) * 16384];
#pragma unroll
        for (int r = 0; r < 2; ++r) {
            short8 pk;
#pragma unroll
            for (int cc = 0; cc < 8; ++cc) pk[cc] = (short)f2bf(xv[r * 8 + cc]);
            int ad = (j * 256 + (cg * 16 + r * 8) * 2) ^ ((j & 15) << 4);
            *(short8*)(lds + ad) = pk;
        }
    }
    {
        const uint4* src = (const uint4*)wupT;
#pragma unroll
        for (int rep = 0; rep < 8; ++rep) {
            int q   = rep * 512 + t;
            int out = q >> 4, c16 = q & 15;
            int ad  = 16384 + ((out * 256 + c16 * 16) ^ ((out & 15) << 4));
            *(uint4*)(lds + ad) = src[q];
        }
    }
    float bvv[4];
#pragma unroll
    for (int ob = 0; ob < 4; ++ob) bvv[ob] = bup[ob * 16 + l15];
    __syncthreads();

    f32x4 acc[2][4];
#pragma unroll
    for (int kk = 0; kk < 2; ++kk)
#pragma unroll
        for (int ob = 0; ob < 4; ++ob) acc[kk][ob] = (f32x4){0.f, 0.f, 0.f, 0.f};

#pragma unroll
    for (int ks = 0; ks < 4; ++ks) {
        const int cb = ks * 64 + (l4 << 4);
        const int rowA = pg * 16 + l15;
        short8 xfr = *(const short8*)(lds + ((rowA * 256 + cb) ^ ((rowA & 15) << 4)));
#pragma unroll
        for (int kk = 0; kk < 2; ++kk)
#pragma unroll
            for (int ob = 0; ob < 4; ++ob) {
                int out = (oh * 2 + kk) * 64 + ob * 16 + l15;
                short8 wfr = *(const short8*)(lds + 16384 +
                              ((out * 256 + cb) ^ ((out & 15) << 4)));
                acc[kk][ob] = __builtin_amdgcn_mfma_f32_16x16x32_bf16(xfr, wfr, acc[kk][ob], 0, 0, 0);
            }
    }
    __syncthreads();

    ushort* OUT = (ushort*)lds;
#pragma unroll
    for (int kk = 0; kk < 2; ++kk) {
        const int k = oh * 2 + kk, p = k >> 1, q = k & 1;
#pragma unroll
        for (int ob = 0; ob < 4; ++ob) {
            const int o = ob * 16 + l15;
#pragma unroll
            for (int r = 0; r < 4; ++r) {
                int jl = pg * 16 + l4 * 4 + r;
                int x  = 2 * jl + q;
                OUT[(p * 128 + x) * 64 + o] = f2bf(acc[kk][ob][r] + bvv[ob]);
            }
        }
    }
    __syncthreads();

#pragma unroll
    for (int rep = 0; rep < 4; ++rep) {
        int idx = rep * 512 + t;
        int p   = idx >> 10;
        int y   = 2 * i + p;
        uint4 v = *(const uint4*)(lds + idx * 16);
        size_t g = (size_t)(z * HF + y) * 2048 + (size_t)j0 * 16 + (idx & 1023);
        ((uint4*)upB)[g] = v;
    }
}

// ---------------------------------------------------------------------------
// 3x3 SAME conv 64->64 + bias + PReLU via bf16 MFMA.
// v3: barrier-free K-loop, ONE tap of weights in registers at a time
// (8 short8 = 32 VGPR, reloaded per tap from L1/L2-resident wT page),
// wave = 2 y-rows x all 64 couts: acc[4 m][4 nf] = 64 VGPR.
// Per tap/wave: 8 ds_read_b128 -> 32 MFMAs (0.25 reads/MFMA).
// Block 256 thr / 4 waves, tile 32x8, LDS = input only (43.5 KB, 3 blocks/CU).
// ---------------------------------------------------------------------------
template<int IN_MODE, int OUT_NHWC>
__global__ __launch_bounds__(256, 3) void k_conv(const float* __restrict__ x2,
                                                 const ushort* __restrict__ upB,
                                                 const ushort* __restrict__ inB,
                                                 const ushort* __restrict__ wT,
                                                 const float* __restrict__ bias,
                                                 const float* __restrict__ alpha,
                                                 ushort* __restrict__ outB,
                                                 float* __restrict__ outF) {
    __shared__ __align__(16) ushort inL[10 * 34 * 64];   // [r][x][c], XOR-swizzled on x

    const int t   = threadIdx.x;
    const int wm  = t >> 6;          // wave id -> y-pair
    const int l   = t & 63;
    const int l15 = l & 15;
    const int l4  = l >> 4;
    const int x0  = (blockIdx.x & 7) * 32;
    const int y0  = (blockIdx.x >> 3) * 8;
    const int b   = blockIdx.y;

    // ---- stage input tile (10 x 34 x 64ch), zero-padded halo
    for (int q = t; q < 10 * 34 * 8; q += 256) {
        int r   = q / 272;
        int rem = q - r * 272;
        int x   = rem >> 3;
        int c8  = rem & 7;
        int gy = y0 - 1 + r;
        int gx = x0 - 1 + x;
        uint4 v = make_uint4(0u, 0u, 0u, 0u);
        if ((unsigned)gy < HF && (unsigned)gx < WF) {
            size_t pos = (size_t)(b * HF + gy) * WF + gx;
            if (IN_MODE == 1) {
                v = *(const uint4*)(inB + pos * 64 + c8 * 8);
            } else if (b < 2) {
                const float4* s = (const float4*)(x2 + pos * 64 + c8 * 8);
                float4 u0 = s[0], u1 = s[1];
                v = make_uint4(pack2(u0.x, u0.y), pack2(u0.z, u0.w),
                               pack2(u1.x, u1.y), pack2(u1.z, u1.w));
            } else {
                size_t p2 = (size_t)((b - 2) * HF + gy) * WF + gx;
                v = *(const uint4*)(upB + p2 * 64 + c8 * 8);
            }
        }
        int ad = (q * 16) ^ ((x & 7) << 4);
        *(uint4*)((char*)inL + ad) = v;
    }
    __syncthreads();

    f32x4 acc[4][4];   // [m][nf]
#pragma unroll
    for (int m = 0; m < 4; ++m)
#pragma unroll
        for (int nf = 0; nf < 4; ++nf) acc[m][nf] = (f32x4){0.f, 0.f, 0.f, 0.f};

    // ---- main loop: no barriers; one tap of weights in regs at a time
#pragma unroll 1
    for (int ky = 0; ky < 3; ++ky) {
#pragma unroll 1
        for (int kx = 0; kx < 3; ++kx) {
            const ushort* wb = wT + (((size_t)(ky * 3 + kx)) << 12) + l15 * 64 + l4 * 8;
            short8 wreg[4][2];
#pragma unroll
            for (int nf = 0; nf < 4; ++nf)
#pragma unroll
                for (int ks = 0; ks < 2; ++ks)
                    wreg[nf][ks] = *(const short8*)(wb + nf * 1024 + ks * 32);
#pragma unroll
            for (int ks = 0; ks < 2; ++ks)
#pragma unroll
                for (int m = 0; m < 4; ++m) {
                    int ry = wm * 2 + (m >> 1) + ky;
                    int xl = (m & 1) * 16 + l15 + kx;
                    int ad = ((ry * 34 + xl) * 128 + ks * 64 + (l4 << 4)) ^ ((xl & 7) << 4);
                    short8 ifr = *(const short8*)((const char*)inL + ad);
#pragma unroll
                    for (int nf = 0; nf < 4; ++nf) {
                        if (OUT_NHWC)
                            acc[m][nf] = __builtin_amdgcn_mfma_f32_16x16x32_bf16(
                                wreg[nf][ks], ifr, acc[m][nf], 0, 0, 0);   // row=cout, col=pos
                        else
                            acc[m][nf] = __builtin_amdgcn_mfma_f32_16x16x32_bf16(
                                ifr, wreg[nf][ks], acc[m][nf], 0, 0, 0);   // row=pos, col=cout
                    }
                }
        }
    }

    const float al = alpha[0];
    if (OUT_NHWC) {
        float4 bv[4];
#pragma unroll
        for (int nf = 0; nf < 4; ++nf) bv[nf] = *(const float4*)(bias + nf * 16 + (l4 << 2));
#pragma unroll
        for (int m = 0; m < 4; ++m) {
            int y = y0 + wm * 2 + (m >> 1);
            int x = x0 + (m & 1) * 16 + l15;
#pragma unroll
            for (int nf = 0; nf < 4; ++nf) {
                f32x4 v = acc[m][nf];
                uint lo = pack2(prelu(v.x + bv[nf].x, al), prelu(v.y + bv[nf].y, al));
                uint hi = pack2(prelu(v.z + bv[nf].z, al), prelu(v.w + bv[nf].w, al));
                int cb = nf * 16 + (l4 << 2);
                *(uint2*)(outB + ((size_t)(b * HF + y) * WF + x) * 64 + cb) = make_uint2(lo, hi);
            }
        }
    } else {
        float bb[4];
#pragma unroll
        for (int nf = 0; nf < 4; ++nf) bb[nf] = bias[nf * 16 + l15];
#pragma unroll
        for (int m = 0; m < 4; ++m) {
            int y  = y0 + wm * 2 + (m >> 1);
            int xb = x0 + (m & 1) * 16 + (l4 << 2);
#pragma unroll
            for (int nf = 0; nf < 4; ++nf) {
                f32x4 v = acc[m][nf];
                int cout = nf * 16 + l15;
                float4 st;
                st.x = prelu(v.x + bb[nf], al);
                st.y = prelu(v.y + bb[nf], al);
                st.z = prelu(v.z + bb[nf], al);
                st.w = prelu(v.w + bb[nf], al);
                *(float4*)(outF + (((size_t)b * 64 + cout) << 16) + y * WF + xb) = st;
            }
        }
    }
}

// ---------------------------------------------------------------------------
extern "C" void kernel_launch(void* const* d_in, const int* in_sizes, int n_in,
                              void* d_out, int out_size, void* d_ws, size_t ws_size,
                              hipStream_t stream) {
    const float* x1  = (const float*)d_in[0];
    const float* x2  = (const float*)d_in[1];
    const float* wup = (const float*)d_in[2];
    const float* bup = (const float*)d_in[3];
    const float* w1  = (const float*)d_in[4];
    const float* b1  = (const float*)d_in[5];
    const float* a1  = (const float*)d_in[6];
    const float* w2  = (const float*)d_in[7];
    const float* b2  = (const float*)d_in[8];
    const float* a2  = (const float*)d_in[9];

    char* ws = (char*)d_ws;
    ushort* upB  = (ushort*)ws;                          // 16 MiB (b=2,3 NHWC bf16)
    ushort* hB   = (ushort*)(ws + (size_t)(16 << 20));   // 32 MiB (NHWC bf16)
    ushort* wT1  = (ushort*)(ws + (size_t)(48 << 20));   // 72 KiB
    ushort* wT2  = wT1 + 9 * 64 * 64;                    // 72 KiB
    ushort* wupT = wT2 + 9 * 64 * 64;                    // 64 KiB
    float* out = (float*)d_out;

    k_wprep<<<144, 256, 0, stream>>>(w1, w2, wT1, wT2);
    k_wprep_up<<<128, 256, 0, stream>>>(wup, wupT);
    k_upsample_mfma<<<dim3(256, 2), 512, 0, stream>>>(x1, wupT, bup, upB);
    k_conv<0, 1><<<dim3(256, 4), 256, 0, stream>>>(x2, upB, nullptr, wT1, b1, a1, hB, nullptr);
    k_conv<1, 0><<<dim3(256, 4), 256, 0, stream>>>(nullptr, nullptr, hB, wT2, b2, a2, nullptr, out);
}

// Round 7
// 129.908 us; speedup vs baseline: 2.1808x; 1.0377x over previous
//
#include <hip/hip_runtime.h>

typedef __attribute__((ext_vector_type(8))) short short8;
typedef __attribute__((ext_vector_type(4))) float f32x4;

#define HF 256
#define WF 256

__device__ __forceinline__ ushort f2bf(float f) {
    uint u = __builtin_bit_cast(uint, f);
    u = (u + 0x7FFFu + ((u >> 16) & 1u)) >> 16;
    return (ushort)u;
}
__device__ __forceinline__ uint pack2(float a, float b) {
    return (uint)f2bf(a) | ((uint)f2bf(b) << 16);
}
__device__ __forceinline__ float prelu(float v, float al) { return v >= 0.f ? v : al * v; }

// ---------------------------------------------------------------------------
// Weight prep A: w[o][c][3][3] f32 -> wT[tap][o][c] bf16 (for the two convs)
// ---------------------------------------------------------------------------
__global__ __launch_bounds__(256) void k_wprep(const float* __restrict__ w1,
                                               const float* __restrict__ w2,
                                               ushort* __restrict__ wT1,
                                               ushort* __restrict__ wT2) {
    int idx = blockIdx.x * 256 + threadIdx.x;   // [tap][o][c] : 9*64*64 = 36864
    int tap = idx >> 12;
    int oc  = idx & 4095;
    int src = oc * 9 + tap;
    wT1[idx] = f2bf(w1[src]);
    wT2[idx] = f2bf(w2[src]);
}

// ---------------------------------------------------------------------------
// Weight prep B: wup[c][o][p][q] f32 -> wupT[out = (p*2+q)*64 + o][c] bf16
// ---------------------------------------------------------------------------
__global__ __launch_bounds__(256) void k_wprep_up(const float* __restrict__ wup,
                                                  ushort* __restrict__ wupT) {
    int idx = blockIdx.x * 256 + threadIdx.x;   // 256*128 = 32768
    int out = idx >> 7;
    int c   = idx & 127;
    int k   = out >> 6;       // p*2+q
    int o   = out & 63;
    wupT[idx] = f2bf(wup[c * 256 + o * 4 + k]);
}

// ---------------------------------------------------------------------------
// ConvTranspose2d k=2 s=2 for b=2,3 via bf16 MFMA -> upB NHWC [z][y][x][64]
// (unchanged — known good)
// ---------------------------------------------------------------------------
__global__ __launch_bounds__(512) void k_upsample_mfma(const float* __restrict__ x1,
                                                       const ushort* __restrict__ wupT,
                                                       const float* __restrict__ bup,
                                                       ushort* __restrict__ upB) {
    __shared__ __align__(16) char lds[81920];

    const int t   = threadIdx.x;
    const int l   = t & 63;
    const int l15 = l & 15;
    const int l4  = l >> 4;
    const int w   = t >> 6;
    const int pg  = w & 3;
    const int oh  = w >> 2;
    const int i   = blockIdx.x >> 1;
    const int j0  = (blockIdx.x & 1) * 64;
    const int z   = blockIdx.y;
    const int gb  = 2 + z;

    {
        const int j  = t & 63;
        const int cg = t >> 6;
        const size_t base = ((size_t)gb * 128) * 16384 + (size_t)i * 128 + j0 + j;
        float xv[16];
#pragma unroll
        for (int r = 0; r < 2; ++r)
#pragma unroll
            for (int cc = 0; cc < 8; ++cc)
                xv[r * 8 + cc] = x1[base + (size_t)(cg * 16 + r * 8 + cc) * 16384];
#pragma unroll
        for (int r = 0; r < 2; ++r) {
            short8 pk;
#pragma unroll
            for (int cc = 0; cc < 8; ++cc) pk[cc] = (short)f2bf(xv[r * 8 + cc]);
            int ad = (j * 256 + (cg * 16 + r * 8) * 2) ^ ((j & 15) << 4);
            *(short8*)(lds + ad) = pk;
        }
    }
    {
        const uint4* src = (const uint4*)wupT;
#pragma unroll
        for (int rep = 0; rep < 8; ++rep) {
            int q   = rep * 512 + t;
            int out = q >> 4, c16 = q & 15;
            int ad  = 16384 + ((out * 256 + c16 * 16) ^ ((out & 15) << 4));
            *(uint4*)(lds + ad) = src[q];
        }
    }
    float bvv[4];
#pragma unroll
    for (int ob = 0; ob < 4; ++ob) bvv[ob] = bup[ob * 16 + l15];
    __syncthreads();

    f32x4 acc[2][4];
#pragma unroll
    for (int kk = 0; kk < 2; ++kk)
#pragma unroll
        for (int ob = 0; ob < 4; ++ob) acc[kk][ob] = (f32x4){0.f, 0.f, 0.f, 0.f};

#pragma unroll
    for (int ks = 0; ks < 4; ++ks) {
        const int cb = ks * 64 + (l4 << 4);
        const int rowA = pg * 16 + l15;
        short8 xfr = *(const short8*)(lds + ((rowA * 256 + cb) ^ ((rowA & 15) << 4)));
#pragma unroll
        for (int kk = 0; kk < 2; ++kk)
#pragma unroll
            for (int ob = 0; ob < 4; ++ob) {
                int out = (oh * 2 + kk) * 64 + ob * 16 + l15;
                short8 wfr = *(const short8*)(lds + 16384 +
                              ((out * 256 + cb) ^ ((out & 15) << 4)));
                acc[kk][ob] = __builtin_amdgcn_mfma_f32_16x16x32_bf16(xfr, wfr, acc[kk][ob], 0, 0, 0);
            }
    }
    __syncthreads();

    ushort* OUT = (ushort*)lds;
#pragma unroll
    for (int kk = 0; kk < 2; ++kk) {
        const int k = oh * 2 + kk, p = k >> 1, q = k & 1;
#pragma unroll
        for (int ob = 0; ob < 4; ++ob) {
            const int o = ob * 16 + l15;
#pragma unroll
            for (int r = 0; r < 4; ++r) {
                int jl = pg * 16 + l4 * 4 + r;
                int x  = 2 * jl + q;
                OUT[(p * 128 + x) * 64 + o] = f2bf(acc[kk][ob][r] + bvv[ob]);
            }
        }
    }
    __syncthreads();

#pragma unroll
    for (int rep = 0; rep < 4; ++rep) {
        int idx = rep * 512 + t;
        int p   = idx >> 10;
        int y   = 2 * i + p;
        uint4 v = *(const uint4*)(lds + idx * 16);
        size_t g = (size_t)(z * HF + y) * 2048 + (size_t)j0 * 16 + (idx & 1023);
        ((uint4*)upB)[g] = v;
    }
}

// ---------------------------------------------------------------------------
// k_conv v4: R6 structure + 2-deep register double-buffer of per-tap weights
// (named wA/wB, rule #20: no runtime-indexed buffers). Zero K-loop barriers.
// Wave = 2 y-rows x all 64 couts, acc[4][4] in AGPRs, 1:4 ds_read:MFMA.
// ---------------------------------------------------------------------------
__device__ __forceinline__ void load_wtap(const ushort* __restrict__ wT, int tap,
                                          int l15, int l4, short8 (&w)[4][2]) {
    const ushort* wb = wT + ((size_t)tap << 12) + l15 * 64 + l4 * 8;
#pragma unroll
    for (int nf = 0; nf < 4; ++nf)
#pragma unroll
        for (int ks = 0; ks < 2; ++ks)
            w[nf][ks] = *(const short8*)(wb + nf * 1024 + ks * 32);
}

template<int OUT_NHWC>
__device__ __forceinline__ void mfma_tap(const ushort* inL, int wm, int l15, int l4,
                                         int tap, const short8 (&w)[4][2],
                                         f32x4 (&acc)[4][4]) {
    const int ky = tap / 3;
    const int kx = tap - ky * 3;
#pragma unroll
    for (int ks = 0; ks < 2; ++ks)
#pragma unroll
        for (int m = 0; m < 4; ++m) {
            int ry = wm * 2 + (m >> 1) + ky;
            int xl = (m & 1) * 16 + l15 + kx;
            int ad = ((ry * 34 + xl) * 128 + ks * 64 + (l4 << 4)) ^ ((xl & 7) << 4);
            short8 ifr = *(const short8*)((const char*)inL + ad);
#pragma unroll
            for (int nf = 0; nf < 4; ++nf) {
                if (OUT_NHWC)
                    acc[m][nf] = __builtin_amdgcn_mfma_f32_16x16x32_bf16(
                        w[nf][ks], ifr, acc[m][nf], 0, 0, 0);   // row=cout, col=pos
                else
                    acc[m][nf] = __builtin_amdgcn_mfma_f32_16x16x32_bf16(
                        ifr, w[nf][ks], acc[m][nf], 0, 0, 0);   // row=pos, col=cout
            }
        }
}

template<int IN_MODE, int OUT_NHWC>
__global__ __launch_bounds__(256, 3) void k_conv(const float* __restrict__ x2,
                                                 const ushort* __restrict__ upB,
                                                 const ushort* __restrict__ inB,
                                                 const ushort* __restrict__ wT,
                                                 const float* __restrict__ bias,
                                                 const float* __restrict__ alpha,
                                                 ushort* __restrict__ outB,
                                                 float* __restrict__ outF) {
    __shared__ __align__(16) ushort inL[10 * 34 * 64];   // [r][x][c], XOR-swizzled on x

    const int t   = threadIdx.x;
    const int wm  = t >> 6;          // wave id -> y-pair
    const int l   = t & 63;
    const int l15 = l & 15;
    const int l4  = l >> 4;
    const int x0  = (blockIdx.x & 7) * 32;
    const int y0  = (blockIdx.x >> 3) * 8;
    const int b   = blockIdx.y;

    // ---- prologue: weights for tap 0 (lands under the staging phase)
    short8 wA[4][2], wB[4][2];
    load_wtap(wT, 0, l15, l4, wA);

    // ---- stage input tile (10 x 34 x 64ch), zero-padded halo
    for (int q = t; q < 10 * 34 * 8; q += 256) {
        int r   = q / 272;
        int rem = q - r * 272;
        int x   = rem >> 3;
        int c8  = rem & 7;
        int gy = y0 - 1 + r;
        int gx = x0 - 1 + x;
        uint4 v = make_uint4(0u, 0u, 0u, 0u);
        if ((unsigned)gy < HF && (unsigned)gx < WF) {
            size_t pos = (size_t)(b * HF + gy) * WF + gx;
            if (IN_MODE == 1) {
                v = *(const uint4*)(inB + pos * 64 + c8 * 8);
            } else if (b < 2) {
                const float4* s = (const float4*)(x2 + pos * 64 + c8 * 8);
                float4 u0 = s[0], u1 = s[1];
                v = make_uint4(pack2(u0.x, u0.y), pack2(u0.z, u0.w),
                               pack2(u1.x, u1.y), pack2(u1.z, u1.w));
            } else {
                size_t p2 = (size_t)((b - 2) * HF + gy) * WF + gx;
                v = *(const uint4*)(upB + p2 * 64 + c8 * 8);
            }
        }
        int ad = (q * 16) ^ ((x & 7) << 4);
        *(uint4*)((char*)inL + ad) = v;
    }
    __syncthreads();

    f32x4 acc[4][4];   // [m][nf]
#pragma unroll
    for (int m = 0; m < 4; ++m)
#pragma unroll
        for (int nf = 0; nf < 4; ++nf) acc[m][nf] = (f32x4){0.f, 0.f, 0.f, 0.f};

    // ---- main loop: no barriers; 2-deep software pipeline on weight regs
#pragma unroll 1
    for (int t2 = 0; t2 < 4; ++t2) {
        const int tap = t2 * 2;
        load_wtap(wT, tap + 1, l15, l4, wB);
        mfma_tap<OUT_NHWC>(inL, wm, l15, l4, tap, wA, acc);
        load_wtap(wT, tap + 2, l15, l4, wA);         // t2=3 loads tap 8
        mfma_tap<OUT_NHWC>(inL, wm, l15, l4, tap + 1, wB, acc);
    }
    mfma_tap<OUT_NHWC>(inL, wm, l15, l4, 8, wA, acc);

    const float al = alpha[0];
    if (OUT_NHWC) {
        float4 bv[4];
#pragma unroll
        for (int nf = 0; nf < 4; ++nf) bv[nf] = *(const float4*)(bias + nf * 16 + (l4 << 2));
#pragma unroll
        for (int m = 0; m < 4; ++m) {
            int y = y0 + wm * 2 + (m >> 1);
            int x = x0 + (m & 1) * 16 + l15;
#pragma unroll
            for (int nf = 0; nf < 4; ++nf) {
                f32x4 v = acc[m][nf];
                uint lo = pack2(prelu(v.x + bv[nf].x, al), prelu(v.y + bv[nf].y, al));
                uint hi = pack2(prelu(v.z + bv[nf].z, al), prelu(v.w + bv[nf].w, al));
                int cb = nf * 16 + (l4 << 2);
                *(uint2*)(outB + ((size_t)(b * HF + y) * WF + x) * 64 + cb) = make_uint2(lo, hi);
            }
        }
    } else {
        float bb[4];
#pragma unroll
        for (int nf = 0; nf < 4; ++nf) bb[nf] = bias[nf * 16 + l15];
#pragma unroll
        for (int m = 0; m < 4; ++m) {
            int y  = y0 + wm * 2 + (m >> 1);
            int xb = x0 + (m & 1) * 16 + (l4 << 2);
#pragma unroll
            for (int nf = 0; nf < 4; ++nf) {
                f32x4 v = acc[m][nf];
                int cout = nf * 16 + l15;
                float4 st;
                st.x = prelu(v.x + bb[nf], al);
                st.y = prelu(v.y + bb[nf], al);
                st.z = prelu(v.z + bb[nf], al);
                st.w = prelu(v.w + bb[nf], al);
                *(float4*)(outF + (((size_t)b * 64 + cout) << 16) + y * WF + xb) = st;
            }
        }
    }
}

// ---------------------------------------------------------------------------
extern "C" void kernel_launch(void* const* d_in, const int* in_sizes, int n_in,
                              void* d_out, int out_size, void* d_ws, size_t ws_size,
                              hipStream_t stream) {
    const float* x1  = (const float*)d_in[0];
    const float* x2  = (const float*)d_in[1];
    const float* wup = (const float*)d_in[2];
    const float* bup = (const float*)d_in[3];
    const float* w1  = (const float*)d_in[4];
    const float* b1  = (const float*)d_in[5];
    const float* a1  = (const float*)d_in[6];
    const float* w2  = (const float*)d_in[7];
    const float* b2  = (const float*)d_in[8];
    const float* a2  = (const float*)d_in[9];

    char* ws = (char*)d_ws;
    ushort* upB  = (ushort*)ws;                          // 16 MiB (b=2,3 NHWC bf16)
    ushort* hB   = (ushort*)(ws + (size_t)(16 << 20));   // 32 MiB (NHWC bf16)
    ushort* wT1  = (ushort*)(ws + (size_t)(48 << 20));   // 72 KiB
    ushort* wT2  = wT1 + 9 * 64 * 64;                    // 72 KiB
    ushort* wupT = wT2 + 9 * 64 * 64;                    // 64 KiB
    float* out = (float*)d_out;

    k_wprep<<<144, 256, 0, stream>>>(w1, w2, wT1, wT2);
    k_wprep_up<<<128, 256, 0, stream>>>(wup, wupT);
    k_upsample_mfma<<<dim3(256, 2), 512, 0, stream>>>(x1, wupT, bup, upB);
    k_conv<0, 1><<<dim3(256, 4), 256, 0, stream>>>(x2, upB, nullptr, wT1, b1, a1, hB, nullptr);
    k_conv<1, 0><<<dim3(256, 4), 256, 0, stream>>>(nullptr, nullptr, hB, wT2, b2, a2, nullptr, out);
}

// Round 8
// 85.143 us; speedup vs baseline: 3.3274x; 1.5258x over previous
//
#include <hip/hip_runtime.h>

typedef __attribute__((ext_vector_type(8))) short short8;
typedef __attribute__((ext_vector_type(4))) float f32x4;

#define HF 256
#define WF 256

__device__ __forceinline__ ushort f2bf(float f) {
    uint u = __builtin_bit_cast(uint, f);
    u = (u + 0x7FFFu + ((u >> 16) & 1u)) >> 16;
    return (ushort)u;
}
__device__ __forceinline__ uint pack2(float a, float b) {
    return (uint)f2bf(a) | ((uint)f2bf(b) << 16);
}
__device__ __forceinline__ float prelu(float v, float al) { return v >= 0.f ? v : al * v; }

// ---------------------------------------------------------------------------
// Weight prep A: w[o][c][3][3] f32 -> wT[tap][o][c] bf16 (for the two convs)
// ---------------------------------------------------------------------------
__global__ __launch_bounds__(256) void k_wprep(const float* __restrict__ w1,
                                               const float* __restrict__ w2,
                                               ushort* __restrict__ wT1,
                                               ushort* __restrict__ wT2) {
    int idx = blockIdx.x * 256 + threadIdx.x;   // [tap][o][c] : 9*64*64 = 36864
    int tap = idx >> 12;
    int oc  = idx & 4095;
    int src = oc * 9 + tap;
    wT1[idx] = f2bf(w1[src]);
    wT2[idx] = f2bf(w2[src]);
}

// ---------------------------------------------------------------------------
// Weight prep B: wup[c][o][p][q] f32 -> wupT[out = (p*2+q)*64 + o][c] bf16
// ---------------------------------------------------------------------------
__global__ __launch_bounds__(256) void k_wprep_up(const float* __restrict__ wup,
                                                  ushort* __restrict__ wupT) {
    int idx = blockIdx.x * 256 + threadIdx.x;   // 256*128 = 32768
    int out = idx >> 7;
    int c   = idx & 127;
    int k   = out >> 6;       // p*2+q
    int o   = out & 63;
    wupT[idx] = f2bf(wup[c * 256 + o * 4 + k]);
}

// ---------------------------------------------------------------------------
// ConvTranspose2d k=2 s=2 for b=2,3 via bf16 MFMA -> upB NHWC [z][y][x][64]
// (unchanged — known good)
// ---------------------------------------------------------------------------
__global__ __launch_bounds__(512) void k_upsample_mfma(const float* __restrict__ x1,
                                                       const ushort* __restrict__ wupT,
                                                       const float* __restrict__ bup,
                                                       ushort* __restrict__ upB) {
    __shared__ __align__(16) char lds[81920];

    const int t   = threadIdx.x;
    const int l   = t & 63;
    const int l15 = l & 15;
    const int l4  = l >> 4;
    const int w   = t >> 6;
    const int pg  = w & 3;
    const int oh  = w >> 2;
    const int i   = blockIdx.x >> 1;
    const int j0  = (blockIdx.x & 1) * 64;
    const int z   = blockIdx.y;
    const int gb  = 2 + z;

    {
        const int j  = t & 63;
        const int cg = t >> 6;
        const size_t base = ((size_t)gb * 128) * 16384 + (size_t)i * 128 + j0 + j;
        float xv[16];
#pragma unroll
        for (int r = 0; r < 2; ++r)
#pragma unroll
            for (int cc = 0; cc < 8; ++cc)
                xv[r * 8 + cc] = x1[base + (size_t)(cg * 16 + r * 8 + cc) * 16384];
#pragma unroll
        for (int r = 0; r < 2; ++r) {
            short8 pk;
#pragma unroll
            for (int cc = 0; cc < 8; ++cc) pk[cc] = (short)f2bf(xv[r * 8 + cc]);
            int ad = (j * 256 + (cg * 16 + r * 8) * 2) ^ ((j & 15) << 4);
            *(short8*)(lds + ad) = pk;
        }
    }
    {
        const uint4* src = (const uint4*)wupT;
#pragma unroll
        for (int rep = 0; rep < 8; ++rep) {
            int q   = rep * 512 + t;
            int out = q >> 4, c16 = q & 15;
            int ad  = 16384 + ((out * 256 + c16 * 16) ^ ((out & 15) << 4));
            *(uint4*)(lds + ad) = src[q];
        }
    }
    float bvv[4];
#pragma unroll
    for (int ob = 0; ob < 4; ++ob) bvv[ob] = bup[ob * 16 + l15];
    __syncthreads();

    f32x4 acc[2][4];
#pragma unroll
    for (int kk = 0; kk < 2; ++kk)
#pragma unroll
        for (int ob = 0; ob < 4; ++ob) acc[kk][ob] = (f32x4){0.f, 0.f, 0.f, 0.f};

#pragma unroll
    for (int ks = 0; ks < 4; ++ks) {
        const int cb = ks * 64 + (l4 << 4);
        const int rowA = pg * 16 + l15;
        short8 xfr = *(const short8*)(lds + ((rowA * 256 + cb) ^ ((rowA & 15) << 4)));
#pragma unroll
        for (int kk = 0; kk < 2; ++kk)
#pragma unroll
            for (int ob = 0; ob < 4; ++ob) {
                int out = (oh * 2 + kk) * 64 + ob * 16 + l15;
                short8 wfr = *(const short8*)(lds + 16384 +
                              ((out * 256 + cb) ^ ((out & 15) << 4)));
                acc[kk][ob] = __builtin_amdgcn_mfma_f32_16x16x32_bf16(xfr, wfr, acc[kk][ob], 0, 0, 0);
            }
    }
    __syncthreads();

    ushort* OUT = (ushort*)lds;
#pragma unroll
    for (int kk = 0; kk < 2; ++kk) {
        const int k = oh * 2 + kk, p = k >> 1, q = k & 1;
#pragma unroll
        for (int ob = 0; ob < 4; ++ob) {
            const int o = ob * 16 + l15;
#pragma unroll
            for (int r = 0; r < 4; ++r) {
                int jl = pg * 16 + l4 * 4 + r;
                int x  = 2 * jl + q;
                OUT[(p * 128 + x) * 64 + o] = f2bf(acc[kk][ob][r] + bvv[ob]);
            }
        }
    }
    __syncthreads();

#pragma unroll
    for (int rep = 0; rep < 4; ++rep) {
        int idx = rep * 512 + t;
        int p   = idx >> 10;
        int y   = 2 * i + p;
        uint4 v = *(const uint4*)(lds + idx * 16);
        size_t g = (size_t)(z * HF + y) * 2048 + (size_t)j0 * 16 + (idx & 1023);
        ((uint4*)upB)[g] = v;
    }
}

// ---------------------------------------------------------------------------
// k_conv v5: block 512 thr / 8 waves, tile 32x16, wave = 2 y-rows x 64 couts.
// ALL 9 taps of weights (72 KB) + input tile (76.5 KB) staged in LDS once,
// ONE barrier, then a pure ds_read+MFMA K-loop: no barriers, no global loads.
// LDS total 148.5 KB -> 1 block/CU. acc[4][4] = 64 AGPR, 0.5 ds_read/MFMA.
// ---------------------------------------------------------------------------
template<int IN_MODE, int OUT_NHWC>
__global__ __launch_bounds__(512, 1) void k_conv(const float* __restrict__ x2,
                                                 const ushort* __restrict__ upB,
                                                 const ushort* __restrict__ inB,
                                                 const ushort* __restrict__ wT,
                                                 const float* __restrict__ bias,
                                                 const float* __restrict__ alpha,
                                                 ushort* __restrict__ outB,
                                                 float* __restrict__ outF) {
    __shared__ __align__(16) ushort inL[18 * 34 * 64];   // 76.5 KB [r][x][c], swz on x
    __shared__ __align__(16) ushort wL[9 * 64 * 64];     // 72  KB [tap][o][c], swz on o

    const int t   = threadIdx.x;
    const int wv  = t >> 6;          // wave id -> y-pair (0..7)
    const int l   = t & 63;
    const int l15 = l & 15;
    const int l4  = l >> 4;
    const int x0  = (blockIdx.x & 7) * 32;
    const int y0  = (blockIdx.x >> 3) * 16;
    const int b   = blockIdx.y;

    // ---- stage ALL weights: 4608 uint4, 9 iters/thread
#pragma unroll
    for (int rep = 0; rep < 9; ++rep) {
        int q    = rep * 512 + t;
        int tap  = q >> 9;
        int qi   = q & 511;
        int o    = qi >> 3;
        int ad   = tap * 8192 + ((qi * 16) ^ ((o & 7) << 4));
        *(uint4*)((char*)wL + ad) = ((const uint4*)wT)[q];
    }

    // ---- stage input tile (18 x 34 x 64ch), zero-padded halo
    for (int q = t; q < 18 * 34 * 8; q += 512) {
        int r   = q / 272;
        int rem = q - r * 272;
        int x   = rem >> 3;
        int c8  = rem & 7;
        int gy = y0 - 1 + r;
        int gx = x0 - 1 + x;
        uint4 v = make_uint4(0u, 0u, 0u, 0u);
        if ((unsigned)gy < HF && (unsigned)gx < WF) {
            size_t pos = (size_t)(b * HF + gy) * WF + gx;
            if (IN_MODE == 1) {
                v = *(const uint4*)(inB + pos * 64 + c8 * 8);
            } else if (b < 2) {
                const float4* s = (const float4*)(x2 + pos * 64 + c8 * 8);
                float4 u0 = s[0], u1 = s[1];
                v = make_uint4(pack2(u0.x, u0.y), pack2(u0.z, u0.w),
                               pack2(u1.x, u1.y), pack2(u1.z, u1.w));
            } else {
                size_t p2 = (size_t)((b - 2) * HF + gy) * WF + gx;
                v = *(const uint4*)(upB + p2 * 64 + c8 * 8);
            }
        }
        int ad = (q * 16) ^ ((x & 7) << 4);
        *(uint4*)((char*)inL + ad) = v;
    }
    __syncthreads();

    f32x4 acc[4][4];   // [m][nf]
#pragma unroll
    for (int m = 0; m < 4; ++m)
#pragma unroll
        for (int nf = 0; nf < 4; ++nf) acc[m][nf] = (f32x4){0.f, 0.f, 0.f, 0.f};

    // ---- K-loop: 9 taps, pure LDS + MFMA, zero barriers
#pragma unroll 1
    for (int tap = 0; tap < 9; ++tap) {
        const int ky = tap / 3;
        const int kx = tap - ky * 3;
        const char* wPage = (const char*)wL + tap * 8192;
#pragma unroll
        for (int ks = 0; ks < 2; ++ks) {
            short8 wfr[4];
#pragma unroll
            for (int nf = 0; nf < 4; ++nf) {
                int o = nf * 16 + l15;
                int ad = (o * 128 + ks * 64 + (l4 << 4)) ^ ((o & 7) << 4);
                wfr[nf] = *(const short8*)(wPage + ad);
            }
#pragma unroll
            for (int m = 0; m < 4; ++m) {
                int ry = wv * 2 + (m >> 1) + ky;
                int xl = (m & 1) * 16 + l15 + kx;
                int ad = ((ry * 34 + xl) * 128 + ks * 64 + (l4 << 4)) ^ ((xl & 7) << 4);
                short8 ifr = *(const short8*)((const char*)inL + ad);
#pragma unroll
                for (int nf = 0; nf < 4; ++nf) {
                    if (OUT_NHWC)
                        acc[m][nf] = __builtin_amdgcn_mfma_f32_16x16x32_bf16(
                            wfr[nf], ifr, acc[m][nf], 0, 0, 0);   // row=cout, col=pos
                    else
                        acc[m][nf] = __builtin_amdgcn_mfma_f32_16x16x32_bf16(
                            ifr, wfr[nf], acc[m][nf], 0, 0, 0);   // row=pos, col=cout
                }
            }
        }
    }

    const float al = alpha[0];
    if (OUT_NHWC) {
        float4 bv[4];
#pragma unroll
        for (int nf = 0; nf < 4; ++nf) bv[nf] = *(const float4*)(bias + nf * 16 + (l4 << 2));
#pragma unroll
        for (int m = 0; m < 4; ++m) {
            int y = y0 + wv * 2 + (m >> 1);
            int x = x0 + (m & 1) * 16 + l15;
#pragma unroll
            for (int nf = 0; nf < 4; ++nf) {
                f32x4 v = acc[m][nf];
                uint lo = pack2(prelu(v.x + bv[nf].x, al), prelu(v.y + bv[nf].y, al));
                uint hi = pack2(prelu(v.z + bv[nf].z, al), prelu(v.w + bv[nf].w, al));
                int cb = nf * 16 + (l4 << 2);
                *(uint2*)(outB + ((size_t)(b * HF + y) * WF + x) * 64 + cb) = make_uint2(lo, hi);
            }
        }
    } else {
        float bb[4];
#pragma unroll
        for (int nf = 0; nf < 4; ++nf) bb[nf] = bias[nf * 16 + l15];
#pragma unroll
        for (int m = 0; m < 4; ++m) {
            int y  = y0 + wv * 2 + (m >> 1);
            int xb = x0 + (m & 1) * 16 + (l4 << 2);
#pragma unroll
            for (int nf = 0; nf < 4; ++nf) {
                f32x4 v = acc[m][nf];
                int cout = nf * 16 + l15;
                float4 st;
                st.x = prelu(v.x + bb[nf], al);
                st.y = prelu(v.y + bb[nf], al);
                st.z = prelu(v.z + bb[nf], al);
                st.w = prelu(v.w + bb[nf], al);
                *(float4*)(outF + (((size_t)b * 64 + cout) << 16) + y * WF + xb) = st;
            }
        }
    }
}

// ---------------------------------------------------------------------------
extern "C" void kernel_launch(void* const* d_in, const int* in_sizes, int n_in,
                              void* d_out, int out_size, void* d_ws, size_t ws_size,
                              hipStream_t stream) {
    const float* x1  = (const float*)d_in[0];
    const float* x2  = (const float*)d_in[1];
    const float* wup = (const float*)d_in[2];
    const float* bup = (const float*)d_in[3];
    const float* w1  = (const float*)d_in[4];
    const float* b1  = (const float*)d_in[5];
    const float* a1  = (const float*)d_in[6];
    const float* w2  = (const float*)d_in[7];
    const float* b2  = (const float*)d_in[8];
    const float* a2  = (const float*)d_in[9];

    char* ws = (char*)d_ws;
    ushort* upB  = (ushort*)ws;                          // 16 MiB (b=2,3 NHWC bf16)
    ushort* hB   = (ushort*)(ws + (size_t)(16 << 20));   // 32 MiB (NHWC bf16)
    ushort* wT1  = (ushort*)(ws + (size_t)(48 << 20));   // 72 KiB
    ushort* wT2  = wT1 + 9 * 64 * 64;                    // 72 KiB
    ushort* wupT = wT2 + 9 * 64 * 64;                    // 64 KiB
    float* out = (float*)d_out;

    k_wprep<<<144, 256, 0, stream>>>(w1, w2, wT1, wT2);
    k_wprep_up<<<128, 256, 0, stream>>>(wup, wupT);
    k_upsample_mfma<<<dim3(256, 2), 512, 0, stream>>>(x1, wupT, bup, upB);
    k_conv<0, 1><<<dim3(128, 4), 512, 0, stream>>>(x2, upB, nullptr, wT1, b1, a1, hB, nullptr);
    k_conv<1, 0><<<dim3(128, 4), 512, 0, stream>>>(nullptr, nullptr, hB, wT2, b2, a2, nullptr, out);
}

// Round 9
// 82.515 us; speedup vs baseline: 3.4333x; 1.0318x over previous
//
#include <hip/hip_runtime.h>

typedef __attribute__((ext_vector_type(8))) short short8;
typedef __attribute__((ext_vector_type(4))) float f32x4;

#define HF 256
#define WF 256

typedef const __attribute__((address_space(1))) void gbl_void;
typedef __attribute__((address_space(3))) void lds_void;

__device__ __forceinline__ ushort f2bf(float f) {
    uint u = __builtin_bit_cast(uint, f);
    u = (u + 0x7FFFu + ((u >> 16) & 1u)) >> 16;
    return (ushort)u;
}
__device__ __forceinline__ uint pack2(float a, float b) {
    return (uint)f2bf(a) | ((uint)f2bf(b) << 16);
}
__device__ __forceinline__ float prelu(float v, float al) { return v >= 0.f ? v : al * v; }

// ---------------------------------------------------------------------------
// Weight prep A: w[o][c][3][3] f32 -> wT[tap][o][c] bf16; also zeroes zeroBuf.
// ---------------------------------------------------------------------------
__global__ __launch_bounds__(256) void k_wprep(const float* __restrict__ w1,
                                               const float* __restrict__ w2,
                                               ushort* __restrict__ wT1,
                                               ushort* __restrict__ wT2,
                                               uint4* __restrict__ zeroBuf) {
    if (blockIdx.x == 0 && threadIdx.x < 16)
        zeroBuf[threadIdx.x] = make_uint4(0u, 0u, 0u, 0u);
    int idx = blockIdx.x * 256 + threadIdx.x;   // [tap][o][c] : 9*64*64 = 36864
    int tap = idx >> 12;
    int oc  = idx & 4095;
    int src = oc * 9 + tap;
    wT1[idx] = f2bf(w1[src]);
    wT2[idx] = f2bf(w2[src]);
}

// ---------------------------------------------------------------------------
// Weight prep B: wup[c][o][p][q] f32 -> wupT[out = (p*2+q)*64 + o][c] bf16
// ---------------------------------------------------------------------------
__global__ __launch_bounds__(256) void k_wprep_up(const float* __restrict__ wup,
                                                  ushort* __restrict__ wupT) {
    int idx = blockIdx.x * 256 + threadIdx.x;   // 256*128 = 32768
    int out = idx >> 7;
    int c   = idx & 127;
    int k   = out >> 6;       // p*2+q
    int o   = out & 63;
    wupT[idx] = f2bf(wup[c * 256 + o * 4 + k]);
}

// ---------------------------------------------------------------------------
// ConvTranspose2d k=2 s=2 for b=2,3 via bf16 MFMA -> upB NHWC [z][y][x][64]
// (unchanged — known good)
// ---------------------------------------------------------------------------
__global__ __launch_bounds__(512) void k_upsample_mfma(const float* __restrict__ x1,
                                                       const ushort* __restrict__ wupT,
                                                       const float* __restrict__ bup,
                                                       ushort* __restrict__ upB) {
    __shared__ __align__(16) char lds[81920];

    const int t   = threadIdx.x;
    const int l   = t & 63;
    const int l15 = l & 15;
    const int l4  = l >> 4;
    const int w   = t >> 6;
    const int pg  = w & 3;
    const int oh  = w >> 2;
    const int i   = blockIdx.x >> 1;
    const int j0  = (blockIdx.x & 1) * 64;
    const int z   = blockIdx.y;
    const int gb  = 2 + z;

    {
        const int j  = t & 63;
        const int cg = t >> 6;
        const size_t base = ((size_t)gb * 128) * 16384 + (size_t)i * 128 + j0 + j;
        float xv[16];
#pragma unroll
        for (int r = 0; r < 2; ++r)
#pragma unroll
            for (int cc = 0; cc < 8; ++cc)
                xv[r * 8 + cc] = x1[base + (size_t)(cg * 16 + r * 8 + cc) * 16384];
#pragma unroll
        for (int r = 0; r < 2; ++r) {
            short8 pk;
#pragma unroll
            for (int cc = 0; cc < 8; ++cc) pk[cc] = (short)f2bf(xv[r * 8 + cc]);
            int ad = (j * 256 + (cg * 16 + r * 8) * 2) ^ ((j & 15) << 4);
            *(short8*)(lds + ad) = pk;
        }
    }
    {
        const uint4* src = (const uint4*)wupT;
#pragma unroll
        for (int rep = 0; rep < 8; ++rep) {
            int q   = rep * 512 + t;
            int out = q >> 4, c16 = q & 15;
            int ad  = 16384 + ((out * 256 + c16 * 16) ^ ((out & 15) << 4));
            *(uint4*)(lds + ad) = src[q];
        }
    }
    float bvv[4];
#pragma unroll
    for (int ob = 0; ob < 4; ++ob) bvv[ob] = bup[ob * 16 + l15];
    __syncthreads();

    f32x4 acc[2][4];
#pragma unroll
    for (int kk = 0; kk < 2; ++kk)
#pragma unroll
        for (int ob = 0; ob < 4; ++ob) acc[kk][ob] = (f32x4){0.f, 0.f, 0.f, 0.f};

#pragma unroll
    for (int ks = 0; ks < 4; ++ks) {
        const int cb = ks * 64 + (l4 << 4);
        const int rowA = pg * 16 + l15;
        short8 xfr = *(const short8*)(lds + ((rowA * 256 + cb) ^ ((rowA & 15) << 4)));
#pragma unroll
        for (int kk = 0; kk < 2; ++kk)
#pragma unroll
            for (int ob = 0; ob < 4; ++ob) {
                int out = (oh * 2 + kk) * 64 + ob * 16 + l15;
                short8 wfr = *(const short8*)(lds + 16384 +
                              ((out * 256 + cb) ^ ((out & 15) << 4)));
                acc[kk][ob] = __builtin_amdgcn_mfma_f32_16x16x32_bf16(xfr, wfr, acc[kk][ob], 0, 0, 0);
            }
    }
    __syncthreads();

    ushort* OUT = (ushort*)lds;
#pragma unroll
    for (int kk = 0; kk < 2; ++kk) {
        const int k = oh * 2 + kk, p = k >> 1, q = k & 1;
#pragma unroll
        for (int ob = 0; ob < 4; ++ob) {
            const int o = ob * 16 + l15;
#pragma unroll
            for (int r = 0; r < 4; ++r) {
                int jl = pg * 16 + l4 * 4 + r;
                int x  = 2 * jl + q;
                OUT[(p * 128 + x) * 64 + o] = f2bf(acc[kk][ob][r] + bvv[ob]);
            }
        }
    }
    __syncthreads();

#pragma unroll
    for (int rep = 0; rep < 4; ++rep) {
        int idx = rep * 512 + t;
        int p   = idx >> 10;
        int y   = 2 * i + p;
        uint4 v = *(const uint4*)(lds + idx * 16);
        size_t g = (size_t)(z * HF + y) * 2048 + (size_t)j0 * 16 + (idx & 1023);
        ((uint4*)upB)[g] = v;
    }
}

// ---------------------------------------------------------------------------
// k_conv v6: R8 structure (512 thr, 32x16 tile, all weights+input in LDS,
// one barrier, barrier-free pure ds_read+MFMA K-loop) with staging switched
// to global_load_lds width=16: LINEAR LDS dest + PRE-SWIZZLED global source
// (rule #21). LDS contents byte-identical to R8. OOB halo -> zeroBuf.
// conv1 b<2 keeps manual f32->bf16 staging (block-uniform branch).
// ---------------------------------------------------------------------------
template<int IN_MODE, int OUT_NHWC>
__global__ __launch_bounds__(512, 1) void k_conv(const float* __restrict__ x2,
                                                 const ushort* __restrict__ upB,
                                                 const ushort* __restrict__ inB,
                                                 const ushort* __restrict__ wT,
                                                 const float* __restrict__ bias,
                                                 const float* __restrict__ alpha,
                                                 const uint4* __restrict__ zeroBuf,
                                                 ushort* __restrict__ outB,
                                                 float* __restrict__ outF) {
    __shared__ __align__(16) ushort inL[5120 * 8];       // 80 KB (4896 used + pad)
    __shared__ __align__(16) ushort wL[9 * 64 * 64];     // 72 KB [tap][o][c], swz on o

    const int t   = threadIdx.x;
    const int wv  = t >> 6;          // wave id -> y-pair (0..7)
    const int l   = t & 63;
    const int l15 = l & 15;
    const int l4  = l >> 4;
    const int x0  = (blockIdx.x & 7) * 32;
    const int y0  = (blockIdx.x >> 3) * 16;
    const int b   = blockIdx.y;

    // ---- stage ALL weights: linear dest, pre-swizzled source
    {
        const char* wTb = (const char*)wT;
#pragma unroll
        for (int rep = 0; rep < 9; ++rep) {
            int d   = rep * 512 + t;                 // dest uint4 index
            int tap = d >> 9;
            int dp  = d & 511;
            int s   = (tap << 9) + (dp ^ ((dp >> 3) & 7));
            __builtin_amdgcn_global_load_lds(
                (gbl_void*)(wTb + (size_t)s * 16),
                (lds_void*)((char*)wL + (size_t)((rep << 9) + (wv << 6)) * 16),
                16, 0, 0);
        }
    }

    // ---- stage input tile (18 x 34 x 64ch = 4896 uint4), halo zero-padded
    if (IN_MODE == 1 || b >= 2) {
        const ushort* src0 = (IN_MODE == 1) ? inB : upB;
        const int bb = (IN_MODE == 1) ? b : (b - 2);
#pragma unroll
        for (int rep = 0; rep < 10; ++rep) {
            int d  = rep * 512 + t;                  // dest uint4 idx (pad >= 4896)
            int r  = d / 272;
            int wi = d - r * 272;
            int wq = wi ^ ((wi >> 3) & 7);           // pre-swizzled source element
            int x  = wq >> 3, c8 = wq & 7;
            int gy = y0 - 1 + r;
            int gx = x0 - 1 + x;
            const void* g;
            if (d < 4896 && (unsigned)gy < HF && (unsigned)gx < WF) {
                size_t pos = (size_t)(bb * HF + gy) * WF + gx;
                g = (const void*)(src0 + pos * 64 + c8 * 8);
            } else {
                g = (const void*)zeroBuf;
            }
            __builtin_amdgcn_global_load_lds(
                (gbl_void*)g,
                (lds_void*)((char*)inL + (size_t)((rep << 9) + (wv << 6)) * 16),
                16, 0, 0);
        }
    } else {
        // manual path: x2 f32 NHWC -> bf16, swizzled ds_write (R8 code)
        for (int q = t; q < 18 * 34 * 8; q += 512) {
            int r   = q / 272;
            int rem = q - r * 272;
            int x   = rem >> 3;
            int c8  = rem & 7;
            int gy = y0 - 1 + r;
            int gx = x0 - 1 + x;
            uint4 v = make_uint4(0u, 0u, 0u, 0u);
            if ((unsigned)gy < HF && (unsigned)gx < WF) {
                size_t pos = (size_t)(b * HF + gy) * WF + gx;
                const float4* s = (const float4*)(x2 + pos * 64 + c8 * 8);
                float4 u0 = s[0], u1 = s[1];
                v = make_uint4(pack2(u0.x, u0.y), pack2(u0.z, u0.w),
                               pack2(u1.x, u1.y), pack2(u1.z, u1.w));
            }
            int ad = (q * 16) ^ ((x & 7) << 4);
            *(uint4*)((char*)inL + ad) = v;
        }
    }
    __syncthreads();

    f32x4 acc[4][4];   // [m][nf]
#pragma unroll
    for (int m = 0; m < 4; ++m)
#pragma unroll
        for (int nf = 0; nf < 4; ++nf) acc[m][nf] = (f32x4){0.f, 0.f, 0.f, 0.f};

    // ---- K-loop: 9 taps, pure LDS + MFMA, zero barriers
#pragma unroll 1
    for (int tap = 0; tap < 9; ++tap) {
        const int ky = tap / 3;
        const int kx = tap - ky * 3;
        const char* wPage = (const char*)wL + tap * 8192;
#pragma unroll
        for (int ks = 0; ks < 2; ++ks) {
            short8 wfr[4];
#pragma unroll
            for (int nf = 0; nf < 4; ++nf) {
                int o = nf * 16 + l15;
                int ad = (o * 128 + ks * 64 + (l4 << 4)) ^ ((o & 7) << 4);
                wfr[nf] = *(const short8*)(wPage + ad);
            }
#pragma unroll
            for (int m = 0; m < 4; ++m) {
                int ry = wv * 2 + (m >> 1) + ky;
                int xl = (m & 1) * 16 + l15 + kx;
                int ad = ((ry * 34 + xl) * 128 + ks * 64 + (l4 << 4)) ^ ((xl & 7) << 4);
                short8 ifr = *(const short8*)((const char*)inL + ad);
#pragma unroll
                for (int nf = 0; nf < 4; ++nf) {
                    if (OUT_NHWC)
                        acc[m][nf] = __builtin_amdgcn_mfma_f32_16x16x32_bf16(
                            wfr[nf], ifr, acc[m][nf], 0, 0, 0);   // row=cout, col=pos
                    else
                        acc[m][nf] = __builtin_amdgcn_mfma_f32_16x16x32_bf16(
                            ifr, wfr[nf], acc[m][nf], 0, 0, 0);   // row=pos, col=cout
                }
            }
        }
    }

    const float al = alpha[0];
    if (OUT_NHWC) {
        float4 bv[4];
#pragma unroll
        for (int nf = 0; nf < 4; ++nf) bv[nf] = *(const float4*)(bias + nf * 16 + (l4 << 2));
#pragma unroll
        for (int m = 0; m < 4; ++m) {
            int y = y0 + wv * 2 + (m >> 1);
            int x = x0 + (m & 1) * 16 + l15;
#pragma unroll
            for (int nf = 0; nf < 4; ++nf) {
                f32x4 v = acc[m][nf];
                uint lo = pack2(prelu(v.x + bv[nf].x, al), prelu(v.y + bv[nf].y, al));
                uint hi = pack2(prelu(v.z + bv[nf].z, al), prelu(v.w + bv[nf].w, al));
                int cb = nf * 16 + (l4 << 2);
                *(uint2*)(outB + ((size_t)(b * HF + y) * WF + x) * 64 + cb) = make_uint2(lo, hi);
            }
        }
    } else {
        float bb[4];
#pragma unroll
        for (int nf = 0; nf < 4; ++nf) bb[nf] = bias[nf * 16 + l15];
#pragma unroll
        for (int m = 0; m < 4; ++m) {
            int y  = y0 + wv * 2 + (m >> 1);
            int xb = x0 + (m & 1) * 16 + (l4 << 2);
#pragma unroll
            for (int nf = 0; nf < 4; ++nf) {
                f32x4 v = acc[m][nf];
                int cout = nf * 16 + l15;
                float4 st;
                st.x = prelu(v.x + bb[nf], al);
                st.y = prelu(v.y + bb[nf], al);
                st.z = prelu(v.z + bb[nf], al);
                st.w = prelu(v.w + bb[nf], al);
                *(float4*)(outF + (((size_t)b * 64 + cout) << 16) + y * WF + xb) = st;
            }
        }
    }
}

// ---------------------------------------------------------------------------
extern "C" void kernel_launch(void* const* d_in, const int* in_sizes, int n_in,
                              void* d_out, int out_size, void* d_ws, size_t ws_size,
                              hipStream_t stream) {
    const float* x1  = (const float*)d_in[0];
    const float* x2  = (const float*)d_in[1];
    const float* wup = (const float*)d_in[2];
    const float* bup = (const float*)d_in[3];
    const float* w1  = (const float*)d_in[4];
    const float* b1  = (const float*)d_in[5];
    const float* a1  = (const float*)d_in[6];
    const float* w2  = (const float*)d_in[7];
    const float* b2  = (const float*)d_in[8];
    const float* a2  = (const float*)d_in[9];

    char* ws = (char*)d_ws;
    ushort* upB  = (ushort*)ws;                          // 16 MiB (b=2,3 NHWC bf16)
    ushort* hB   = (ushort*)(ws + (size_t)(16 << 20));   // 32 MiB (NHWC bf16)
    ushort* wT1  = (ushort*)(ws + (size_t)(48 << 20));   // 72 KiB
    ushort* wT2  = wT1 + 9 * 64 * 64;                    // 72 KiB
    ushort* wupT = wT2 + 9 * 64 * 64;                    // 64 KiB
    uint4*  zeroBuf = (uint4*)(ws + (size_t)(49 << 20)); // 256 B, zeroed by k_wprep
    float* out = (float*)d_out;

    k_wprep<<<144, 256, 0, stream>>>(w1, w2, wT1, wT2, zeroBuf);
    k_wprep_up<<<128, 256, 0, stream>>>(wup, wupT);
    k_upsample_mfma<<<dim3(256, 2), 512, 0, stream>>>(x1, wupT, bup, upB);
    k_conv<0, 1><<<dim3(128, 4), 512, 0, stream>>>(x2, upB, nullptr, wT1, b1, a1, zeroBuf, hB, nullptr);
    k_conv<1, 0><<<dim3(128, 4), 512, 0, stream>>>(nullptr, nullptr, hB, wT2, b2, a2, zeroBuf, nullptr, out);
}